// Round 3
// baseline (38.415 us; speedup 1.0000x reference)
//
#include <hip/hip_runtime.h>

// Q_s_a[b] = relu(node_emb[idx[b]] * (state[b]·W4)) · W5
//
// Key algebraic identity: with s = state[b]·W4 a SCALAR,
//   relu(ne * s) = (s>=0) ? s*relu(ne) : (-s)*relu(-ne)
// so   q[b] = (s>=0) ? s*A[idx[b]] : (-s)*B[idx[b]]
// where A[n] = sum_e relu(+node[n][e])*W5[e]
//       B[n] = sum_e relu(-node[n][e])*W5[e]
// are batch-independent per-node scalars.
//
// Kernel 1 streams the 51.2 MB node table once and writes the 1.6 MB AB
// table to d_ws. Kernel 2 streams state (102.4 MB, coalesced) and gathers
// only 8 B per row from the AB table (L2-resident: 1.6 MB < 4 MiB/XCD),
// replacing the 256 B random node-row gather (32x less gather traffic).

typedef float f4 __attribute__((ext_vector_type(4)));

__global__ __launch_bounds__(256) void Decoding_precompute_AB(
    const float* __restrict__ node,   // [N, 64]
    const float* __restrict__ W5,     // [64]
    float2*      __restrict__ AB,     // [N] {A, B}
    int N)
{
    const int lane16 = threadIdx.x & 15;
    const int n = (int)((blockIdx.x * blockDim.x + threadIdx.x) >> 4);
    if (n >= N) return;

    const f4 w5 = reinterpret_cast<const f4*>(W5)[lane16];
    const f4 ne = reinterpret_cast<const f4*>(node + (size_t)n * 64)[lane16];

    float a = fmaxf(ne.x, 0.f) * w5.x + fmaxf(ne.y, 0.f) * w5.y
            + fmaxf(ne.z, 0.f) * w5.z + fmaxf(ne.w, 0.f) * w5.w;
    float b = fmaxf(-ne.x, 0.f) * w5.x + fmaxf(-ne.y, 0.f) * w5.y
            + fmaxf(-ne.z, 0.f) * w5.z + fmaxf(-ne.w, 0.f) * w5.w;

    #pragma unroll
    for (int o = 1; o < 16; o <<= 1) {
        a += __shfl_xor(a, o);   // two independent reduction chains:
        b += __shfl_xor(b, o);   // they pipeline, no added critical path
    }
    if (lane16 == 0) AB[n] = make_float2(a, b);
}

__global__ __launch_bounds__(256) void Decoding_main(
    const int*    __restrict__ idx,    // [B]
    const float*  __restrict__ state,  // [B, 64]
    const float*  __restrict__ W4,     // [64]
    const float2* __restrict__ AB,     // [N]
    float*        __restrict__ out,    // [B]
    int B)
{
    const int lane16 = threadIdx.x & 15;
    const int row = (int)((blockIdx.x * blockDim.x + threadIdx.x) >> 4);
    if (row >= B) return;

    const f4 w4 = reinterpret_cast<const f4*>(W4)[lane16];

    const int a = idx[row];            // broadcast within group
    const float2 ab = AB[a];           // 8 B L2-hit gather, issued before the
                                       // reduction (independent of s)
    const f4 se = reinterpret_cast<const f4*>(state + (size_t)row * 64)[lane16];

    float s = se.x * w4.x + se.y * w4.y + se.z * w4.z + se.w * w4.w;
    #pragma unroll
    for (int o = 1; o < 16; o <<= 1) s += __shfl_xor(s, o);

    if (lane16 == 0)
        out[row] = (s >= 0.f) ? s * ab.x : (-s) * ab.y;
}

// Fallback (ws too small): original fused gather kernel with the A/B trick
// computed inline per row.
__global__ __launch_bounds__(256) void Decoding_fused_fallback(
    const int*   __restrict__ idx,
    const float* __restrict__ node,
    const float* __restrict__ state,
    const float* __restrict__ W4,
    const float* __restrict__ W5,
    float*       __restrict__ out,
    int B)
{
    const int lane16 = threadIdx.x & 15;
    const int row = (int)((blockIdx.x * blockDim.x + threadIdx.x) >> 4);
    if (row >= B) return;

    const f4 w4 = reinterpret_cast<const f4*>(W4)[lane16];
    const f4 w5 = reinterpret_cast<const f4*>(W5)[lane16];

    const int a = idx[row];
    const f4 se = reinterpret_cast<const f4*>(state + (size_t)row * 64)[lane16];
    const f4 ne = reinterpret_cast<const f4*>(node + (size_t)a * 64)[lane16];

    float s = se.x * w4.x + se.y * w4.y + se.z * w4.z + se.w * w4.w;
    float pa = fmaxf(ne.x, 0.f) * w5.x + fmaxf(ne.y, 0.f) * w5.y
             + fmaxf(ne.z, 0.f) * w5.z + fmaxf(ne.w, 0.f) * w5.w;
    float pb = fmaxf(-ne.x, 0.f) * w5.x + fmaxf(-ne.y, 0.f) * w5.y
             + fmaxf(-ne.z, 0.f) * w5.z + fmaxf(-ne.w, 0.f) * w5.w;
    #pragma unroll
    for (int o = 1; o < 16; o <<= 1) {   // three independent chains, 4 steps
        s += __shfl_xor(s, o);
        pa += __shfl_xor(pa, o);
        pb += __shfl_xor(pb, o);
    }
    if (lane16 == 0)
        out[row] = (s >= 0.f) ? s * pa : (-s) * pb;
}

extern "C" void kernel_launch(void* const* d_in, const int* in_sizes, int n_in,
                              void* d_out, int out_size, void* d_ws, size_t ws_size,
                              hipStream_t stream) {
    const int*   idx   = (const int*)  d_in[0];  // actions_idx     [B]
    const float* node  = (const float*)d_in[1];  // node_embedding  [N,64]
    const float* state = (const float*)d_in[2];  // state_embedding [B,64]
    const float* W4    = (const float*)d_in[3];  // [64,1]
    const float* W5    = (const float*)d_in[4];  // [64,1]
    float*       out   = (float*)d_out;          // [B,1]

    const int B = in_sizes[0];
    const int N = in_sizes[1] / 64;

    if (ws_size >= (size_t)N * sizeof(float2)) {
        float2* AB = (float2*)d_ws;
        // 16 lanes per row -> rows_per_block = 256/16 = 16
        const int blk1 = (N + 15) / 16;   // 12500 blocks
        Decoding_precompute_AB<<<blk1, 256, 0, stream>>>(node, W5, AB, N);
        const int blk2 = (B + 15) / 16;   // 25000 blocks
        Decoding_main<<<blk2, 256, 0, stream>>>(idx, state, W4, AB, out, B);
    } else {
        const int blk = (B + 15) / 16;
        Decoding_fused_fallback<<<blk, 256, 0, stream>>>(
            idx, node, state, W4, W5, out, B);
    }
}

// Round 4
// 34.748 us; speedup vs baseline: 1.1055x; 1.1055x over previous
//
#include <hip/hip_runtime.h>

// Q_s_a[b] = relu(node_emb[idx[b]] * (state[b]·W4)) · W5
//
// Algebraic split: with s = state[b]·W4 a SCALAR,
//   relu(ne * s) = (s>=0) ? s*relu(ne) : (-s)*relu(-ne)
// so   q[b] = (s>=0) ? s*A[idx[b]] : (-s)*B[idx[b]]
// where A[n] = sum_e relu(+node[n][e])*W5[e]
//       B[n] = sum_e relu(-node[n][e])*W5[e]  are batch-independent.
//
// This cuts DELIVERED bytes vs the fused kernel: the per-row gather drops
// from a 256 B node row (102.4 MB logical through the fabric) to one 64 B
// line of the 1.6 MB L2-resident AB table (~25.6 MB, L2-side only).
// Fused delivered ~208 MB @ 6 TB/s = 34.8 us (R1, ~95% of ceiling);
// split delivers ~155 MB HBM/L3-side -> predicted ~29-31 us.
//
// R3 lesson: launch shape matters — both kernels are 2048-block grid-stride
// (the exact shape that hit 95% of ceiling in R1), not 25k one-shot blocks.

typedef float f4 __attribute__((ext_vector_type(4)));

__global__ __launch_bounds__(256) void Decoding_precompute_AB(
    const float* __restrict__ node,   // [N, 64]
    const float* __restrict__ W5,     // [64]
    float2*      __restrict__ AB,     // [N] {A, B}
    int N)
{
    const int lane16 = threadIdx.x & 15;
    const f4 w5 = reinterpret_cast<const f4*>(W5)[lane16];

    const int group   = (blockIdx.x * blockDim.x + threadIdx.x) >> 4;
    const int ngroups = (gridDim.x * blockDim.x) >> 4;

    for (int n = group; n < N; n += ngroups) {
        const f4 ne = reinterpret_cast<const f4*>(node + (size_t)n * 64)[lane16];

        float a = fmaxf(ne.x, 0.f) * w5.x + fmaxf(ne.y, 0.f) * w5.y
                + fmaxf(ne.z, 0.f) * w5.z + fmaxf(ne.w, 0.f) * w5.w;
        float b = fmaxf(-ne.x, 0.f) * w5.x + fmaxf(-ne.y, 0.f) * w5.y
                + fmaxf(-ne.z, 0.f) * w5.z + fmaxf(-ne.w, 0.f) * w5.w;

        #pragma unroll
        for (int o = 1; o < 16; o <<= 1) {   // two independent chains, pipeline
            a += __shfl_xor(a, o);
            b += __shfl_xor(b, o);
        }
        if (lane16 == 0) AB[n] = make_float2(a, b);
    }
}

__global__ __launch_bounds__(256) void Decoding_main(
    const int*    __restrict__ idx,    // [B]
    const float*  __restrict__ state,  // [B, 64]
    const float*  __restrict__ W4,     // [64]
    const float2* __restrict__ AB,     // [N]
    float*        __restrict__ out,    // [B]
    int B)
{
    const int lane16 = threadIdx.x & 15;
    const f4 w4 = reinterpret_cast<const f4*>(W4)[lane16];

    const int group   = (blockIdx.x * blockDim.x + threadIdx.x) >> 4;
    const int ngroups = (gridDim.x * blockDim.x) >> 4;

    for (int row = group; row < B; row += ngroups) {
        const int a = idx[row];            // broadcast within 16-lane group
        const float2 ab = AB[a];           // 8 B gather, L2-resident table
        const f4 se =
            reinterpret_cast<const f4*>(state + (size_t)row * 64)[lane16];

        float s = se.x * w4.x + se.y * w4.y + se.z * w4.z + se.w * w4.w;
        #pragma unroll
        for (int o = 1; o < 16; o <<= 1) s += __shfl_xor(s, o);

        if (lane16 == 0)
            out[row] = (s >= 0.f) ? s * ab.x : (-s) * ab.y;
    }
}

// Fallback (ws too small): fused gather kernel, 3 interleaved reduce chains.
__global__ __launch_bounds__(256) void Decoding_fused_fallback(
    const int*   __restrict__ idx,
    const float* __restrict__ node,
    const float* __restrict__ state,
    const float* __restrict__ W4,
    const float* __restrict__ W5,
    float*       __restrict__ out,
    int B)
{
    const int lane16 = threadIdx.x & 15;
    const f4 w4 = reinterpret_cast<const f4*>(W4)[lane16];
    const f4 w5 = reinterpret_cast<const f4*>(W5)[lane16];

    const int group   = (blockIdx.x * blockDim.x + threadIdx.x) >> 4;
    const int ngroups = (gridDim.x * blockDim.x) >> 4;

    for (int row = group; row < B; row += ngroups) {
        const int a = idx[row];
        const f4 se =
            reinterpret_cast<const f4*>(state + (size_t)row * 64)[lane16];
        const f4 ne =
            reinterpret_cast<const f4*>(node + (size_t)a * 64)[lane16];

        float s = se.x * w4.x + se.y * w4.y + se.z * w4.z + se.w * w4.w;
        float pa = fmaxf(ne.x, 0.f) * w5.x + fmaxf(ne.y, 0.f) * w5.y
                 + fmaxf(ne.z, 0.f) * w5.z + fmaxf(ne.w, 0.f) * w5.w;
        float pb = fmaxf(-ne.x, 0.f) * w5.x + fmaxf(-ne.y, 0.f) * w5.y
                 + fmaxf(-ne.z, 0.f) * w5.z + fmaxf(-ne.w, 0.f) * w5.w;
        #pragma unroll
        for (int o = 1; o < 16; o <<= 1) {
            s  += __shfl_xor(s, o);
            pa += __shfl_xor(pa, o);
            pb += __shfl_xor(pb, o);
        }
        if (lane16 == 0)
            out[row] = (s >= 0.f) ? s * pa : (-s) * pb;
    }
}

extern "C" void kernel_launch(void* const* d_in, const int* in_sizes, int n_in,
                              void* d_out, int out_size, void* d_ws, size_t ws_size,
                              hipStream_t stream) {
    const int*   idx   = (const int*)  d_in[0];  // actions_idx     [B]
    const float* node  = (const float*)d_in[1];  // node_embedding  [N,64]
    const float* state = (const float*)d_in[2];  // state_embedding [B,64]
    const float* W4    = (const float*)d_in[3];  // [64,1]
    const float* W5    = (const float*)d_in[4];  // [64,1]
    float*       out   = (float*)d_out;          // [B,1]

    const int B = in_sizes[0];
    const int N = in_sizes[1] / 64;

    const int block  = 256;
    const int blocks = 2048;   // grid-stride; full occupancy at VGPR=16

    if (ws_size >= (size_t)N * sizeof(float2)) {
        float2* AB = (float2*)d_ws;
        Decoding_precompute_AB<<<blocks, block, 0, stream>>>(node, W5, AB, N);
        Decoding_main<<<blocks, block, 0, stream>>>(idx, state, W4, AB, out, B);
    } else {
        Decoding_fused_fallback<<<blocks, block, 0, stream>>>(
            idx, node, state, W4, W5, out, B);
    }
}